// Round 1
// baseline (213.129 us; speedup 1.0000x reference)
//
#include <hip/hip_runtime.h>

// SS2D: B=32,H=32,W=32,DM=128, DIN=64, N=16, R=8, L=1024
// ws layout (floats): xc/y share 0, z @2M, u @4M, delta @6M, Bs @8M, Cs @8M+512K

#define L_ 1024
#define BSZ 32

// ---------------- K1: xz = x @ w_in^T ; split into xc (NCHW) and z (b,l,d) ----
__global__ __launch_bounds__(256) void k1_gemm_in(
    const float* __restrict__ x, const float* __restrict__ w_in,
    float* __restrict__ xc, float* __restrict__ z)
{
    __shared__ float As[32 * 68];    // [k][m], stride 68
    __shared__ float Ws[32 * 132];   // [k][e], stride 132
    const int t  = threadIdx.x;
    const int p0 = blockIdx.x * 64;
    const int tx = t & 15, ty = t >> 4;

    float acc[4][8];
#pragma unroll
    for (int i = 0; i < 4; ++i)
#pragma unroll
        for (int j = 0; j < 8; ++j) acc[i][j] = 0.f;

    for (int kk = 0; kk < 128; kk += 32) {
        // stage x tile transposed: rows m=t>>3 and m+32, cols (t&7)*4
        {
            const int m  = t >> 3;
            const int c4 = (t & 7) * 4;
            const float4 v0 = *reinterpret_cast<const float4*>(&x[(size_t)(p0 + m) * 128 + kk + c4]);
            const float4 v1 = *reinterpret_cast<const float4*>(&x[(size_t)(p0 + m + 32) * 128 + kk + c4]);
            As[(c4 + 0) * 68 + m] = v0.x; As[(c4 + 1) * 68 + m] = v0.y;
            As[(c4 + 2) * 68 + m] = v0.z; As[(c4 + 3) * 68 + m] = v0.w;
            As[(c4 + 0) * 68 + m + 32] = v1.x; As[(c4 + 1) * 68 + m + 32] = v1.y;
            As[(c4 + 2) * 68 + m + 32] = v1.z; As[(c4 + 3) * 68 + m + 32] = v1.w;
        }
        // stage w_in tile transposed
        for (int i = t; i < 4096; i += 256) {
            const int c = i & 31, e = i >> 5;
            Ws[c * 132 + e] = w_in[(size_t)e * 128 + kk + c];
        }
        __syncthreads();
#pragma unroll
        for (int k = 0; k < 32; ++k) {
            const float4 a  = *reinterpret_cast<const float4*>(&As[k * 68 + (ty << 2)]);
            const float4 b0 = *reinterpret_cast<const float4*>(&Ws[k * 132 + (tx << 3)]);
            const float4 b1 = *reinterpret_cast<const float4*>(&Ws[k * 132 + (tx << 3) + 4]);
            const float am[4] = {a.x, a.y, a.z, a.w};
            const float bm[8] = {b0.x, b0.y, b0.z, b0.w, b1.x, b1.y, b1.z, b1.w};
#pragma unroll
            for (int i = 0; i < 4; ++i)
#pragma unroll
                for (int j = 0; j < 8; ++j)
                    acc[i][j] = fmaf(am[i], bm[j], acc[i][j]);
        }
        __syncthreads();
    }

    const int b  = p0 >> 10;
    const int l0 = (p0 & 1023) + (ty << 2);
    if (tx < 8) {
        // xc channels e = tx*8+j, NCHW: contiguous along l
#pragma unroll
        for (int j = 0; j < 8; ++j) {
            const int e = (tx << 3) + j;
            *reinterpret_cast<float4*>(&xc[((size_t)b * 64 + e) * 1024 + l0]) =
                make_float4(acc[0][j], acc[1][j], acc[2][j], acc[3][j]);
        }
    } else {
        // z: (b,l,d) contiguous along d
        const int d0 = (tx - 8) << 3;
#pragma unroll
        for (int i = 0; i < 4; ++i) {
            const size_t p = (size_t)p0 + (ty << 2) + i;
            *reinterpret_cast<float4*>(&z[p * 64 + d0]) =
                make_float4(acc[i][0], acc[i][1], acc[i][2], acc[i][3]);
            *reinterpret_cast<float4*>(&z[p * 64 + d0 + 4]) =
                make_float4(acc[i][4], acc[i][5], acc[i][6], acc[i][7]);
        }
    }
}

// ---------------- K2: depthwise 3x3 conv + bias + SiLU -> u (b,d,l) ----------
__global__ __launch_bounds__(256) void k2_conv(
    const float* __restrict__ xc, const float* __restrict__ cw,
    const float* __restrict__ cb, float* __restrict__ u)
{
    __shared__ float pl[1024];
    const int bd = blockIdx.x;
    const int t  = threadIdx.x;
    const int d  = bd & 63;
    reinterpret_cast<float4*>(pl)[t] =
        reinterpret_cast<const float4*>(xc + (size_t)bd * 1024)[t];
    float w[9];
#pragma unroll
    for (int i = 0; i < 9; ++i) w[i] = cw[d * 9 + i];
    const float bias = cb[d];
    __syncthreads();
    float o[4];
#pragma unroll
    for (int i = 0; i < 4; ++i) {
        const int p  = t * 4 + i;
        const int py = p >> 5, px = p & 31;
        float s = 0.f;
#pragma unroll
        for (int ky = 0; ky < 3; ++ky) {
            const int iy = py + ky - 1;
            if (iy < 0 || iy > 31) continue;
#pragma unroll
            for (int kx = 0; kx < 3; ++kx) {
                const int ix = px + kx - 1;
                if (ix < 0 || ix > 31) continue;
                s = fmaf(pl[iy * 32 + ix], w[ky * 3 + kx], s);
            }
        }
        s += bias;
        o[i] = s / (1.f + __expf(-s));
    }
    reinterpret_cast<float4*>(u + (size_t)bd * 1024)[t] = make_float4(o[0], o[1], o[2], o[3]);
}

// ---------------- K3: x-proj (40 ch) + dt-proj + softplus --------------------
__global__ __launch_bounds__(256) void k3_xproj(
    const float* __restrict__ u, const float* __restrict__ xpw,
    const float* __restrict__ dtw_g, const float* __restrict__ dtb,
    float* __restrict__ delta, float* __restrict__ Bsp, float* __restrict__ Csp)
{
    __shared__ float xw[64 * 40];  // [d][c]
    __shared__ float dw[64 * 8];   // [d][r]
    const int t = threadIdx.x;
    for (int i = t; i < 2560; i += 256) {
        const int dd = i / 40, c = i - dd * 40;
        xw[i] = xpw[(size_t)c * 64 + dd];
    }
    for (int i = t; i < 512; i += 256) dw[i] = dtw_g[i];
    __syncthreads();

    const int gid = blockIdx.x * 256 + t;
    const int b = gid >> 10, l = gid & 1023;

    float4 acc[10];
#pragma unroll
    for (int i = 0; i < 10; ++i) acc[i] = make_float4(0.f, 0.f, 0.f, 0.f);

    const float* up = u + (size_t)b * 65536 + l;
    for (int dd = 0; dd < 64; ++dd) {
        const float uv = up[(size_t)dd * 1024];
        const float4* row = reinterpret_cast<const float4*>(&xw[dd * 40]);
#pragma unroll
        for (int i = 0; i < 10; ++i) {
            const float4 wv = row[i];
            acc[i].x = fmaf(uv, wv.x, acc[i].x);
            acc[i].y = fmaf(uv, wv.y, acc[i].y);
            acc[i].z = fmaf(uv, wv.z, acc[i].z);
            acc[i].w = fmaf(uv, wv.w, acc[i].w);
        }
    }

    // Bs = channels 8..23, Cs = 24..39
    float* bp = Bsp + (size_t)b * 16384 + l;
    bp[0*1024]=acc[2].x; bp[1*1024]=acc[2].y; bp[2*1024]=acc[2].z; bp[3*1024]=acc[2].w;
    bp[4*1024]=acc[3].x; bp[5*1024]=acc[3].y; bp[6*1024]=acc[3].z; bp[7*1024]=acc[3].w;
    bp[8*1024]=acc[4].x; bp[9*1024]=acc[4].y; bp[10*1024]=acc[4].z; bp[11*1024]=acc[4].w;
    bp[12*1024]=acc[5].x; bp[13*1024]=acc[5].y; bp[14*1024]=acc[5].z; bp[15*1024]=acc[5].w;
    float* cp = Csp + (size_t)b * 16384 + l;
    cp[0*1024]=acc[6].x; cp[1*1024]=acc[6].y; cp[2*1024]=acc[6].z; cp[3*1024]=acc[6].w;
    cp[4*1024]=acc[7].x; cp[5*1024]=acc[7].y; cp[6*1024]=acc[7].z; cp[7*1024]=acc[7].w;
    cp[8*1024]=acc[8].x; cp[9*1024]=acc[8].y; cp[10*1024]=acc[8].z; cp[11*1024]=acc[8].w;
    cp[12*1024]=acc[9].x; cp[13*1024]=acc[9].y; cp[14*1024]=acc[9].z; cp[15*1024]=acc[9].w;

    const float dts[8] = {acc[0].x, acc[0].y, acc[0].z, acc[0].w,
                          acc[1].x, acc[1].y, acc[1].z, acc[1].w};
    float* dp = delta + (size_t)b * 65536 + l;
    for (int dd = 0; dd < 64; ++dd) {
        const float4* r = reinterpret_cast<const float4*>(&dw[dd * 8]);
        const float4 w0 = r[0], w1 = r[1];
        float s = dtb[dd];
        s = fmaf(dts[0], w0.x, s); s = fmaf(dts[1], w0.y, s);
        s = fmaf(dts[2], w0.z, s); s = fmaf(dts[3], w0.w, s);
        s = fmaf(dts[4], w1.x, s); s = fmaf(dts[5], w1.y, s);
        s = fmaf(dts[6], w1.z, s); s = fmaf(dts[7], w1.w, s);
        const float sp = fmaxf(s, 0.f) + log1pf(__expf(-fabsf(s)));
        dp[(size_t)dd * 1024] = sp;
    }
}

// ---------------- K4: selective scan over L; y written as (b,l,d) ------------
__global__ __launch_bounds__(256) void k4_scan(
    const float* __restrict__ delta, const float* __restrict__ u,
    const float* __restrict__ Bsp, const float* __restrict__ Csp,
    const float* __restrict__ A_logs, const float* __restrict__ Ds,
    float* __restrict__ y)
{
    const int t = threadIdx.x;
    const int lane = t & 63;
    const int wv = t >> 6;
    const int dloc = lane >> 4, n = lane & 15;
    const int pair = (blockIdx.x * 4 + wv) * 4 + dloc;
    const int b = pair >> 6, d = pair & 63;

    const float Aval = -__expf(A_logs[d * 16 + n]);
    const float Dval = Ds[d];
    const float4* dp = reinterpret_cast<const float4*>(delta + ((size_t)b * 64 + d) * 1024);
    const float4* up = reinterpret_cast<const float4*>(u + ((size_t)b * 64 + d) * 1024);
    const float4* Bp = reinterpret_cast<const float4*>(Bsp + ((size_t)b * 16 + n) * 1024);
    const float4* Cp = reinterpret_cast<const float4*>(Csp + ((size_t)b * 16 + n) * 1024);
    float* yp = y + (size_t)b * 65536 + d;

    float h = 0.f;
#define SCAN_STEP(DJ, UJ, BJ, CJ, YJ)                                   \
    {                                                                   \
        const float dA = __expf((DJ) * Aval);                           \
        h = fmaf(dA, h, (DJ) * (UJ) * (BJ));                            \
        float pz = h * (CJ);                                            \
        pz += __shfl_xor(pz, 1); pz += __shfl_xor(pz, 2);               \
        pz += __shfl_xor(pz, 4); pz += __shfl_xor(pz, 8);               \
        YJ = fmaf(Dval, (UJ), pz);                                      \
    }
    for (int l4 = 0; l4 < 256; ++l4) {
        const float4 dv = dp[l4], uv = up[l4], bv = Bp[l4], cv = Cp[l4];
        float y0, y1, y2, y3;
        SCAN_STEP(dv.x, uv.x, bv.x, cv.x, y0)
        SCAN_STEP(dv.y, uv.y, bv.y, cv.y, y1)
        SCAN_STEP(dv.z, uv.z, bv.z, cv.z, y2)
        SCAN_STEP(dv.w, uv.w, bv.w, cv.w, y3)
        if (n == 0) {
            const size_t l = (size_t)l4 * 4;
            yp[(l + 0) * 64] = y0;
            yp[(l + 1) * 64] = y1;
            yp[(l + 2) * 64] = y2;
            yp[(l + 3) * 64] = y3;
        }
    }
#undef SCAN_STEP
}

// ---------------- K5: LayerNorm + silu(z) gate + out GEMM --------------------
__global__ __launch_bounds__(256) void k5_out(
    const float* __restrict__ y, const float* __restrict__ z,
    const float* __restrict__ ln_g, const float* __restrict__ ln_b,
    const float* __restrict__ w_out, float* __restrict__ out)
{
    __shared__ float yn[64 * 65];   // [p][d] pad 65
    __shared__ float wo[64 * 132];  // [d][c] pad 132
    const int t  = threadIdx.x;
    const int p0 = blockIdx.x * 64;

    for (int i = t; i < 8192; i += 256) {
        const int c = i >> 6, dd = i & 63;
        wo[dd * 132 + c] = w_out[i];
    }

    const int lane = t & 63, wv = t >> 6;
    const float g = ln_g[lane], bbv = ln_b[lane];
#pragma unroll 1
    for (int i = 0; i < 16; ++i) {
        const int pl = wv * 16 + i;
        const size_t p = (size_t)p0 + pl;
        const float v  = y[p * 64 + lane];
        const float zv = z[p * 64 + lane];
        float s1 = v, s2 = v * v;
#pragma unroll
        for (int m = 1; m < 64; m <<= 1) {
            s1 += __shfl_xor(s1, m);
            s2 += __shfl_xor(s2, m);
        }
        const float mu   = s1 * (1.f / 64.f);
        const float var  = s2 * (1.f / 64.f) - mu * mu;
        const float rstd = rsqrtf(var + 1e-5f);
        const float sz   = zv / (1.f + __expf(-zv));
        yn[pl * 65 + lane] = ((v - mu) * rstd * g + bbv) * sz;
    }
    __syncthreads();

    const int tx = t & 31, ty = t >> 5;
    float acc[8][4];
#pragma unroll
    for (int i = 0; i < 8; ++i)
#pragma unroll
        for (int j = 0; j < 4; ++j) acc[i][j] = 0.f;

    for (int dd = 0; dd < 64; ++dd) {
        const float4 w4 = *reinterpret_cast<const float4*>(&wo[dd * 132 + (tx << 2)]);
#pragma unroll
        for (int i = 0; i < 8; ++i) {
            const float a = yn[(ty * 8 + i) * 65 + dd];
            acc[i][0] = fmaf(a, w4.x, acc[i][0]);
            acc[i][1] = fmaf(a, w4.y, acc[i][1]);
            acc[i][2] = fmaf(a, w4.z, acc[i][2]);
            acc[i][3] = fmaf(a, w4.w, acc[i][3]);
        }
    }
#pragma unroll
    for (int i = 0; i < 8; ++i) {
        const size_t p = (size_t)p0 + ty * 8 + i;
        *reinterpret_cast<float4*>(&out[p * 128 + (tx << 2)]) =
            make_float4(acc[i][0], acc[i][1], acc[i][2], acc[i][3]);
    }
}

extern "C" void kernel_launch(void* const* d_in, const int* in_sizes, int n_in,
                              void* d_out, int out_size, void* d_ws, size_t ws_size,
                              hipStream_t stream)
{
    const float* x        = (const float*)d_in[0];
    const float* w_in     = (const float*)d_in[1];
    const float* conv_w   = (const float*)d_in[2];
    const float* conv_b   = (const float*)d_in[3];
    const float* xproj_w  = (const float*)d_in[4];
    const float* dtproj_w = (const float*)d_in[5];
    const float* dtproj_b = (const float*)d_in[6];
    const float* A_logs   = (const float*)d_in[7];
    const float* Ds       = (const float*)d_in[8];
    const float* ln_g     = (const float*)d_in[9];
    const float* ln_b     = (const float*)d_in[10];
    const float* w_out    = (const float*)d_in[11];
    float* out = (float*)d_out;
    float* ws  = (float*)d_ws;

    const size_t M  = (size_t)2097152;  // 32*64*1024
    float* xc    = ws;                  // 8 MB  (reused as y after conv is consumed)
    float* z     = ws + M;              // 8 MB
    float* u     = ws + 2 * M;          // 8 MB
    float* delta = ws + 3 * M;          // 8 MB
    float* y     = ws + 4 * M;          // 8 MB
    float* Bsp   = ws + 5 * M;          // 2 MB
    float* Csp   = Bsp + 524288;        // 2 MB

    k1_gemm_in<<<512, 256, 0, stream>>>(x, w_in, xc, z);
    k2_conv<<<2048, 256, 0, stream>>>(xc, conv_w, conv_b, u);
    k3_xproj<<<128, 256, 0, stream>>>(u, xproj_w, dtproj_w, dtproj_b, delta, Bsp, Csp);
    k4_scan<<<128, 256, 0, stream>>>(delta, u, Bsp, Csp, A_logs, Ds, y);
    k5_out<<<512, 256, 0, stream>>>(y, z, ln_g, ln_b, w_out, out);
}

// Round 4
// 191.825 us; speedup vs baseline: 1.1111x; 1.1111x over previous
//
#include <hip/hip_runtime.h>

// SS2D: B=32,H=32,W=32,DM=128, DIN=64, N=16, R=8, L=1024

// ---------------- K1: xz = x @ w_in^T ; split into xc (NCHW) and z (b,l,d) ----
__global__ __launch_bounds__(256) void k1_gemm_in(
    const float* __restrict__ x, const float* __restrict__ w_in,
    float* __restrict__ xc, float* __restrict__ z)
{
    __shared__ float As[32 * 68];    // [k][m], stride 68
    __shared__ float Ws[32 * 132];   // [k][e], stride 132
    const int t  = threadIdx.x;
    const int p0 = blockIdx.x * 64;
    const int tx = t & 15, ty = t >> 4;

    float acc[4][8];
#pragma unroll
    for (int i = 0; i < 4; ++i)
#pragma unroll
        for (int j = 0; j < 8; ++j) acc[i][j] = 0.f;

    for (int kk = 0; kk < 128; kk += 32) {
        {
            const int m  = t >> 3;
            const int c4 = (t & 7) * 4;
            const float4 v0 = *reinterpret_cast<const float4*>(&x[(size_t)(p0 + m) * 128 + kk + c4]);
            const float4 v1 = *reinterpret_cast<const float4*>(&x[(size_t)(p0 + m + 32) * 128 + kk + c4]);
            As[(c4 + 0) * 68 + m] = v0.x; As[(c4 + 1) * 68 + m] = v0.y;
            As[(c4 + 2) * 68 + m] = v0.z; As[(c4 + 3) * 68 + m] = v0.w;
            As[(c4 + 0) * 68 + m + 32] = v1.x; As[(c4 + 1) * 68 + m + 32] = v1.y;
            As[(c4 + 2) * 68 + m + 32] = v1.z; As[(c4 + 3) * 68 + m + 32] = v1.w;
        }
        for (int i = t; i < 4096; i += 256) {
            const int c = i & 31, e = i >> 5;
            Ws[c * 132 + e] = w_in[(size_t)e * 128 + kk + c];
        }
        __syncthreads();
#pragma unroll
        for (int k = 0; k < 32; ++k) {
            const float4 a  = *reinterpret_cast<const float4*>(&As[k * 68 + (ty << 2)]);
            const float4 b0 = *reinterpret_cast<const float4*>(&Ws[k * 132 + (tx << 3)]);
            const float4 b1 = *reinterpret_cast<const float4*>(&Ws[k * 132 + (tx << 3) + 4]);
            const float am[4] = {a.x, a.y, a.z, a.w};
            const float bm[8] = {b0.x, b0.y, b0.z, b0.w, b1.x, b1.y, b1.z, b1.w};
#pragma unroll
            for (int i = 0; i < 4; ++i)
#pragma unroll
                for (int j = 0; j < 8; ++j)
                    acc[i][j] = fmaf(am[i], bm[j], acc[i][j]);
        }
        __syncthreads();
    }

    const int b  = p0 >> 10;
    const int l0 = (p0 & 1023) + (ty << 2);
    if (tx < 8) {
#pragma unroll
        for (int j = 0; j < 8; ++j) {
            const int e = (tx << 3) + j;
            *reinterpret_cast<float4*>(&xc[((size_t)b * 64 + e) * 1024 + l0]) =
                make_float4(acc[0][j], acc[1][j], acc[2][j], acc[3][j]);
        }
    } else {
        const int d0 = (tx - 8) << 3;
#pragma unroll
        for (int i = 0; i < 4; ++i) {
            const size_t p = (size_t)p0 + (ty << 2) + i;
            *reinterpret_cast<float4*>(&z[p * 64 + d0]) =
                make_float4(acc[i][0], acc[i][1], acc[i][2], acc[i][3]);
            *reinterpret_cast<float4*>(&z[p * 64 + d0 + 4]) =
                make_float4(acc[i][4], acc[i][5], acc[i][6], acc[i][7]);
        }
    }
}

// ---------------- K2: depthwise 3x3 conv + bias + SiLU -> u (b,d,l) ----------
__global__ __launch_bounds__(256) void k2_conv(
    const float* __restrict__ xc, const float* __restrict__ cw,
    const float* __restrict__ cb, float* __restrict__ u)
{
    __shared__ float pl[1024];
    const int bd = blockIdx.x;
    const int t  = threadIdx.x;
    const int d  = bd & 63;
    reinterpret_cast<float4*>(pl)[t] =
        reinterpret_cast<const float4*>(xc + (size_t)bd * 1024)[t];
    float w[9];
#pragma unroll
    for (int i = 0; i < 9; ++i) w[i] = cw[d * 9 + i];
    const float bias = cb[d];
    __syncthreads();
    float o[4];
#pragma unroll
    for (int i = 0; i < 4; ++i) {
        const int p  = t * 4 + i;
        const int py = p >> 5, px = p & 31;
        float s = 0.f;
#pragma unroll
        for (int ky = 0; ky < 3; ++ky) {
            const int iy = py + ky - 1;
            if (iy < 0 || iy > 31) continue;
#pragma unroll
            for (int kx = 0; kx < 3; ++kx) {
                const int ix = px + kx - 1;
                if (ix < 0 || ix > 31) continue;
                s = fmaf(pl[iy * 32 + ix], w[ky * 3 + kx], s);
            }
        }
        s += bias;
        o[i] = s / (1.f + __expf(-s));
    }
    reinterpret_cast<float4*>(u + (size_t)bd * 1024)[t] = make_float4(o[0], o[1], o[2], o[3]);
}

// ---------------- K3: x-proj (40 ch) + dt-proj + softplus --------------------
__global__ __launch_bounds__(256) void k3_xproj(
    const float* __restrict__ u, const float* __restrict__ xpw,
    const float* __restrict__ dtw_g, const float* __restrict__ dtb,
    float* __restrict__ delta, float* __restrict__ Bsp, float* __restrict__ Csp)
{
    __shared__ float xw[64 * 40];  // [d][c]
    __shared__ float dw[64 * 8];   // [d][r]
    const int t = threadIdx.x;
    for (int i = t; i < 2560; i += 256) {
        const int dd = i / 40, c = i - dd * 40;
        xw[i] = xpw[(size_t)c * 64 + dd];
    }
    for (int i = t; i < 512; i += 256) dw[i] = dtw_g[i];
    __syncthreads();

    const int gid = blockIdx.x * 256 + t;
    const int b = gid >> 10, l = gid & 1023;

    float4 acc[10];
#pragma unroll
    for (int i = 0; i < 10; ++i) acc[i] = make_float4(0.f, 0.f, 0.f, 0.f);

    const float* up = u + (size_t)b * 65536 + l;
    for (int dd = 0; dd < 64; ++dd) {
        const float uv = up[(size_t)dd * 1024];
        const float4* row = reinterpret_cast<const float4*>(&xw[dd * 40]);
#pragma unroll
        for (int i = 0; i < 10; ++i) {
            const float4 wv = row[i];
            acc[i].x = fmaf(uv, wv.x, acc[i].x);
            acc[i].y = fmaf(uv, wv.y, acc[i].y);
            acc[i].z = fmaf(uv, wv.z, acc[i].z);
            acc[i].w = fmaf(uv, wv.w, acc[i].w);
        }
    }

    float* bp = Bsp + (size_t)b * 16384 + l;
    bp[0*1024]=acc[2].x; bp[1*1024]=acc[2].y; bp[2*1024]=acc[2].z; bp[3*1024]=acc[2].w;
    bp[4*1024]=acc[3].x; bp[5*1024]=acc[3].y; bp[6*1024]=acc[3].z; bp[7*1024]=acc[3].w;
    bp[8*1024]=acc[4].x; bp[9*1024]=acc[4].y; bp[10*1024]=acc[4].z; bp[11*1024]=acc[4].w;
    bp[12*1024]=acc[5].x; bp[13*1024]=acc[5].y; bp[14*1024]=acc[5].z; bp[15*1024]=acc[5].w;
    float* cp = Csp + (size_t)b * 16384 + l;
    cp[0*1024]=acc[6].x; cp[1*1024]=acc[6].y; cp[2*1024]=acc[6].z; cp[3*1024]=acc[6].w;
    cp[4*1024]=acc[7].x; cp[5*1024]=acc[7].y; cp[6*1024]=acc[7].z; cp[7*1024]=acc[7].w;
    cp[8*1024]=acc[8].x; cp[9*1024]=acc[8].y; cp[10*1024]=acc[8].z; cp[11*1024]=acc[8].w;
    cp[12*1024]=acc[9].x; cp[13*1024]=acc[9].y; cp[14*1024]=acc[9].z; cp[15*1024]=acc[9].w;

    const float dts[8] = {acc[0].x, acc[0].y, acc[0].z, acc[0].w,
                          acc[1].x, acc[1].y, acc[1].z, acc[1].w};
    float* dp = delta + (size_t)b * 65536 + l;
    for (int dd = 0; dd < 64; ++dd) {
        const float4* r = reinterpret_cast<const float4*>(&dw[dd * 8]);
        const float4 w0 = r[0], w1 = r[1];
        float s = dtb[dd];
        s = fmaf(dts[0], w0.x, s); s = fmaf(dts[1], w0.y, s);
        s = fmaf(dts[2], w0.z, s); s = fmaf(dts[3], w0.w, s);
        s = fmaf(dts[4], w1.x, s); s = fmaf(dts[5], w1.y, s);
        s = fmaf(dts[6], w1.z, s); s = fmaf(dts[7], w1.w, s);
        const float sp = fmaxf(s, 0.f) + log1pf(__expf(-fabsf(s)));
        dp[(size_t)dd * 1024] = sp;
    }
}

// ---------------- K4: chunked selective scan (one block per (b,d)) -----------
// thread t = (chunk c = t>>4, state n = t&15). Chunk = 64 timesteps.
// Pass 1: per-chunk affine reduction (P = prod dA, q = in-chunk response).
// LDS exchange -> each lane composes preceding chunks for its incoming h.
// Pass 2: re-run chunk with real h, 16-lane shfl reduce for y_t, += Ds*u.
__global__ __launch_bounds__(256) void k4_scan(
    const float* __restrict__ delta, const float* __restrict__ u,
    const float* __restrict__ Bsp, const float* __restrict__ Csp,
    const float* __restrict__ A_logs, const float* __restrict__ Ds,
    float* __restrict__ y)
{
    __shared__ float Pb[16][17];
    __shared__ float qb[16][17];
    const int t = threadIdx.x;
    const int c = t >> 4;           // chunk index 0..15
    const int n = t & 15;           // state index 0..15
    const int pair = blockIdx.x;    // b*64 + d
    const int b = pair >> 6, d = pair & 63;

    const float Aval = -__expf(A_logs[d * 16 + n]);
    const float Dval = Ds[d];

    const float4* dp = reinterpret_cast<const float4*>(delta + ((size_t)b * 64 + d) * 1024 + c * 64);
    const float4* up = reinterpret_cast<const float4*>(u     + ((size_t)b * 64 + d) * 1024 + c * 64);
    const float4* Bp = reinterpret_cast<const float4*>(Bsp + ((size_t)b * 16 + n) * 1024 + c * 64);
    const float4* Cp = reinterpret_cast<const float4*>(Csp + ((size_t)b * 16 + n) * 1024 + c * 64);
    float* yp = y + ((size_t)b * 1024 + (size_t)c * 64) * 64 + d;

    // ---- pass 1: chunk -> (P, q) ----
    float P = 1.f, q = 0.f;
#define P1_STEP(DJ, UJ, BJ)                          \
    {                                                \
        const float a = __expf((DJ) * Aval);         \
        P *= a;                                      \
        q = fmaf(a, q, (DJ) * (UJ) * (BJ));          \
    }
    for (int j4 = 0; j4 < 16; ++j4) {
        const float4 dv = dp[j4], uv = up[j4], bv = Bp[j4];
        P1_STEP(dv.x, uv.x, bv.x)
        P1_STEP(dv.y, uv.y, bv.y)
        P1_STEP(dv.z, uv.z, bv.z)
        P1_STEP(dv.w, uv.w, bv.w)
    }
#undef P1_STEP
    Pb[c][n] = P; qb[c][n] = q;
    __syncthreads();

    // incoming h for this chunk: compose chunks 0..c-1 applied to h=0
    float h = 0.f;
    for (int cc = 0; cc < c; ++cc)
        h = fmaf(Pb[cc][n], h, qb[cc][n]);

    // ---- pass 2: re-run chunk with real h ----
#define P2_STEP(DJ, UJ, BJ, CJ, YJ)                        \
    {                                                      \
        const float a = __expf((DJ) * Aval);               \
        h = fmaf(a, h, (DJ) * (UJ) * (BJ));                \
        float pz = h * (CJ);                               \
        pz += __shfl_xor(pz, 1); pz += __shfl_xor(pz, 2);  \
        pz += __shfl_xor(pz, 4); pz += __shfl_xor(pz, 8);  \
        YJ = fmaf(Dval, (UJ), pz);                         \
    }
    for (int j4 = 0; j4 < 16; ++j4) {
        const float4 dv = dp[j4], uv = up[j4], bv = Bp[j4], cv = Cp[j4];
        float y0, y1, y2, y3;
        P2_STEP(dv.x, uv.x, bv.x, cv.x, y0)
        P2_STEP(dv.y, uv.y, bv.y, cv.y, y1)
        P2_STEP(dv.z, uv.z, bv.z, cv.z, y2)
        P2_STEP(dv.w, uv.w, bv.w, cv.w, y3)
        if (n == 0) {
            const size_t l = (size_t)j4 * 4;
            yp[(l + 0) * 64] = y0;
            yp[(l + 1) * 64] = y1;
            yp[(l + 2) * 64] = y2;
            yp[(l + 3) * 64] = y3;
        }
    }
#undef P2_STEP
}

// ---------------- K5: LayerNorm + silu(z) gate + out GEMM --------------------
__global__ __launch_bounds__(256) void k5_out(
    const float* __restrict__ y, const float* __restrict__ z,
    const float* __restrict__ ln_g, const float* __restrict__ ln_b,
    const float* __restrict__ w_out, float* __restrict__ out)
{
    __shared__ float yn[64 * 65];   // [p][d] pad 65
    __shared__ float wo[64 * 132];  // [d][c] pad 132
    const int t  = threadIdx.x;
    const int p0 = blockIdx.x * 64;

    for (int i = t; i < 8192; i += 256) {
        const int c = i >> 6, dd = i & 63;
        wo[dd * 132 + c] = w_out[i];
    }

    const int lane = t & 63, wv = t >> 6;
    const float g = ln_g[lane], bbv = ln_b[lane];
#pragma unroll 1
    for (int i = 0; i < 16; ++i) {
        const int pl = wv * 16 + i;
        const size_t p = (size_t)p0 + pl;
        const float v  = y[p * 64 + lane];
        const float zv = z[p * 64 + lane];
        float s1 = v, s2 = v * v;
#pragma unroll
        for (int m = 1; m < 64; m <<= 1) {
            s1 += __shfl_xor(s1, m);
            s2 += __shfl_xor(s2, m);
        }
        const float mu   = s1 * (1.f / 64.f);
        const float var  = s2 * (1.f / 64.f) - mu * mu;
        const float rstd = rsqrtf(var + 1e-5f);
        const float sz   = zv / (1.f + __expf(-zv));
        yn[pl * 65 + lane] = ((v - mu) * rstd * g + bbv) * sz;
    }
    __syncthreads();

    const int tx = t & 31, ty = t >> 5;
    float acc[8][4];
#pragma unroll
    for (int i = 0; i < 8; ++i)
#pragma unroll
        for (int j = 0; j < 4; ++j) acc[i][j] = 0.f;

    for (int dd = 0; dd < 64; ++dd) {
        const float4 w4 = *reinterpret_cast<const float4*>(&wo[dd * 132 + (tx << 2)]);
#pragma unroll
        for (int i = 0; i < 8; ++i) {
            const float a = yn[(ty * 8 + i) * 65 + dd];
            acc[i][0] = fmaf(a, w4.x, acc[i][0]);
            acc[i][1] = fmaf(a, w4.y, acc[i][1]);
            acc[i][2] = fmaf(a, w4.z, acc[i][2]);
            acc[i][3] = fmaf(a, w4.w, acc[i][3]);
        }
    }
#pragma unroll
    for (int i = 0; i < 8; ++i) {
        const size_t p = (size_t)p0 + ty * 8 + i;
        *reinterpret_cast<float4*>(&out[p * 128 + (tx << 2)]) =
            make_float4(acc[i][0], acc[i][1], acc[i][2], acc[i][3]);
    }
}

extern "C" void kernel_launch(void* const* d_in, const int* in_sizes, int n_in,
                              void* d_out, int out_size, void* d_ws, size_t ws_size,
                              hipStream_t stream)
{
    const float* x        = (const float*)d_in[0];
    const float* w_in     = (const float*)d_in[1];
    const float* conv_w   = (const float*)d_in[2];
    const float* conv_b   = (const float*)d_in[3];
    const float* xproj_w  = (const float*)d_in[4];
    const float* dtproj_w = (const float*)d_in[5];
    const float* dtproj_b = (const float*)d_in[6];
    const float* A_logs   = (const float*)d_in[7];
    const float* Ds       = (const float*)d_in[8];
    const float* ln_g     = (const float*)d_in[9];
    const float* ln_b     = (const float*)d_in[10];
    const float* w_out    = (const float*)d_in[11];
    float* out = (float*)d_out;
    float* ws  = (float*)d_ws;

    const size_t M  = (size_t)2097152;  // 32*64*1024
    float* xc    = ws;                  // 8 MB
    float* z     = ws + M;              // 8 MB
    float* u     = ws + 2 * M;          // 8 MB
    float* delta = ws + 3 * M;          // 8 MB
    float* y     = ws + 4 * M;          // 8 MB
    float* Bsp   = ws + 5 * M;          // 2 MB
    float* Csp   = Bsp + 524288;        // 2 MB

    k1_gemm_in<<<512, 256, 0, stream>>>(x, w_in, xc, z);
    k2_conv<<<2048, 256, 0, stream>>>(xc, conv_w, conv_b, u);
    k3_xproj<<<128, 256, 0, stream>>>(u, xproj_w, dtproj_w, dtproj_b, delta, Bsp, Csp);
    k4_scan<<<2048, 256, 0, stream>>>(delta, u, Bsp, Csp, A_logs, Ds, y);
    k5_out<<<512, 256, 0, stream>>>(y, z, ln_g, ln_b, w_out, out);
}

// Round 5
// 185.605 us; speedup vs baseline: 1.1483x; 1.0335x over previous
//
#include <hip/hip_runtime.h>

// SS2D: B=32,H=32,W=32,DM=128, DIN=64, N=16, R=8, L=1024
// Layouts: xc,u,delta,y = (b,d,l); z = (b,l,d); Bs,Cs = (b,n,l); out = (b,l,dm)

// ---------------- K1: xz = x @ w_in^T ; split into xc (NCHW) and z (b,l,d) ----
__global__ __launch_bounds__(256) void k1_gemm_in(
    const float* __restrict__ x, const float* __restrict__ w_in,
    float* __restrict__ xc, float* __restrict__ z)
{
    __shared__ float As[32 * 68];    // [k][m], stride 68
    __shared__ float Ws[32 * 132];   // [k][e], stride 132
    const int t  = threadIdx.x;
    const int p0 = blockIdx.x * 64;
    const int tx = t & 15, ty = t >> 4;

    float acc[4][8];
#pragma unroll
    for (int i = 0; i < 4; ++i)
#pragma unroll
        for (int j = 0; j < 8; ++j) acc[i][j] = 0.f;

    for (int kk = 0; kk < 128; kk += 32) {
        {
            const int m  = t >> 3;
            const int c4 = (t & 7) * 4;
            const float4 v0 = *reinterpret_cast<const float4*>(&x[(size_t)(p0 + m) * 128 + kk + c4]);
            const float4 v1 = *reinterpret_cast<const float4*>(&x[(size_t)(p0 + m + 32) * 128 + kk + c4]);
            As[(c4 + 0) * 68 + m] = v0.x; As[(c4 + 1) * 68 + m] = v0.y;
            As[(c4 + 2) * 68 + m] = v0.z; As[(c4 + 3) * 68 + m] = v0.w;
            As[(c4 + 0) * 68 + m + 32] = v1.x; As[(c4 + 1) * 68 + m + 32] = v1.y;
            As[(c4 + 2) * 68 + m + 32] = v1.z; As[(c4 + 3) * 68 + m + 32] = v1.w;
        }
        for (int i = t; i < 4096; i += 256) {
            const int c = i & 31, e = i >> 5;
            Ws[c * 132 + e] = w_in[(size_t)e * 128 + kk + c];
        }
        __syncthreads();
#pragma unroll
        for (int k = 0; k < 32; ++k) {
            const float4 a  = *reinterpret_cast<const float4*>(&As[k * 68 + (ty << 2)]);
            const float4 b0 = *reinterpret_cast<const float4*>(&Ws[k * 132 + (tx << 3)]);
            const float4 b1 = *reinterpret_cast<const float4*>(&Ws[k * 132 + (tx << 3) + 4]);
            const float am[4] = {a.x, a.y, a.z, a.w};
            const float bm[8] = {b0.x, b0.y, b0.z, b0.w, b1.x, b1.y, b1.z, b1.w};
#pragma unroll
            for (int i = 0; i < 4; ++i)
#pragma unroll
                for (int j = 0; j < 8; ++j)
                    acc[i][j] = fmaf(am[i], bm[j], acc[i][j]);
        }
        __syncthreads();
    }

    const int b  = p0 >> 10;
    const int l0 = (p0 & 1023) + (ty << 2);
    if (tx < 8) {
#pragma unroll
        for (int j = 0; j < 8; ++j) {
            const int e = (tx << 3) + j;
            *reinterpret_cast<float4*>(&xc[((size_t)b * 64 + e) * 1024 + l0]) =
                make_float4(acc[0][j], acc[1][j], acc[2][j], acc[3][j]);
        }
    } else {
        const int d0 = (tx - 8) << 3;
#pragma unroll
        for (int i = 0; i < 4; ++i) {
            const size_t p = (size_t)p0 + (ty << 2) + i;
            *reinterpret_cast<float4*>(&z[p * 64 + d0]) =
                make_float4(acc[i][0], acc[i][1], acc[i][2], acc[i][3]);
            *reinterpret_cast<float4*>(&z[p * 64 + d0 + 4]) =
                make_float4(acc[i][4], acc[i][5], acc[i][6], acc[i][7]);
        }
    }
}

// ---------------- K2: depthwise 3x3 conv + bias + SiLU -> u (b,d,l) ----------
__global__ __launch_bounds__(256) void k2_conv(
    const float* __restrict__ xc, const float* __restrict__ cw,
    const float* __restrict__ cb, float* __restrict__ u)
{
    __shared__ float pl[1024];
    const int bd = blockIdx.x;
    const int t  = threadIdx.x;
    const int d  = bd & 63;
    reinterpret_cast<float4*>(pl)[t] =
        reinterpret_cast<const float4*>(xc + (size_t)bd * 1024)[t];
    float w[9];
#pragma unroll
    for (int i = 0; i < 9; ++i) w[i] = cw[d * 9 + i];
    const float bias = cb[d];
    __syncthreads();
    float o[4];
#pragma unroll
    for (int i = 0; i < 4; ++i) {
        const int p  = t * 4 + i;
        const int py = p >> 5, px = p & 31;
        float s = 0.f;
#pragma unroll
        for (int ky = 0; ky < 3; ++ky) {
            const int iy = py + ky - 1;
            if (iy < 0 || iy > 31) continue;
#pragma unroll
            for (int kx = 0; kx < 3; ++kx) {
                const int ix = px + kx - 1;
                if (ix < 0 || ix > 31) continue;
                s = fmaf(pl[iy * 32 + ix], w[ky * 3 + kx], s);
            }
        }
        s += bias;
        o[i] = s / (1.f + __expf(-s));
    }
    reinterpret_cast<float4*>(u + (size_t)bd * 1024)[t] = make_float4(o[0], o[1], o[2], o[3]);
}

// ---------------- K3: x-proj (40 ch) + dt-proj + softplus --------------------
__global__ __launch_bounds__(256) void k3_xproj(
    const float* __restrict__ u, const float* __restrict__ xpw,
    const float* __restrict__ dtw_g, const float* __restrict__ dtb,
    float* __restrict__ delta, float* __restrict__ Bsp, float* __restrict__ Csp)
{
    __shared__ float xw[64 * 40];  // [d][c]
    __shared__ float dw[64 * 8];   // [d][r]
    const int t = threadIdx.x;
    for (int i = t; i < 2560; i += 256) {
        const int dd = i / 40, c = i - dd * 40;
        xw[i] = xpw[(size_t)c * 64 + dd];
    }
    for (int i = t; i < 512; i += 256) dw[i] = dtw_g[i];
    __syncthreads();

    const int gid = blockIdx.x * 256 + t;
    const int b = gid >> 10, l = gid & 1023;

    float4 acc[10];
#pragma unroll
    for (int i = 0; i < 10; ++i) acc[i] = make_float4(0.f, 0.f, 0.f, 0.f);

    const float* up = u + (size_t)b * 65536 + l;
    for (int dd = 0; dd < 64; ++dd) {
        const float uv = up[(size_t)dd * 1024];
        const float4* row = reinterpret_cast<const float4*>(&xw[dd * 40]);
#pragma unroll
        for (int i = 0; i < 10; ++i) {
            const float4 wv = row[i];
            acc[i].x = fmaf(uv, wv.x, acc[i].x);
            acc[i].y = fmaf(uv, wv.y, acc[i].y);
            acc[i].z = fmaf(uv, wv.z, acc[i].z);
            acc[i].w = fmaf(uv, wv.w, acc[i].w);
        }
    }

    float* bp = Bsp + (size_t)b * 16384 + l;
    bp[0*1024]=acc[2].x; bp[1*1024]=acc[2].y; bp[2*1024]=acc[2].z; bp[3*1024]=acc[2].w;
    bp[4*1024]=acc[3].x; bp[5*1024]=acc[3].y; bp[6*1024]=acc[3].z; bp[7*1024]=acc[3].w;
    bp[8*1024]=acc[4].x; bp[9*1024]=acc[4].y; bp[10*1024]=acc[4].z; bp[11*1024]=acc[4].w;
    bp[12*1024]=acc[5].x; bp[13*1024]=acc[5].y; bp[14*1024]=acc[5].z; bp[15*1024]=acc[5].w;
    float* cp = Csp + (size_t)b * 16384 + l;
    cp[0*1024]=acc[6].x; cp[1*1024]=acc[6].y; cp[2*1024]=acc[6].z; cp[3*1024]=acc[6].w;
    cp[4*1024]=acc[7].x; cp[5*1024]=acc[7].y; cp[6*1024]=acc[7].z; cp[7*1024]=acc[7].w;
    cp[8*1024]=acc[8].x; cp[9*1024]=acc[8].y; cp[10*1024]=acc[8].z; cp[11*1024]=acc[8].w;
    cp[12*1024]=acc[9].x; cp[13*1024]=acc[9].y; cp[14*1024]=acc[9].z; cp[15*1024]=acc[9].w;

    const float dts[8] = {acc[0].x, acc[0].y, acc[0].z, acc[0].w,
                          acc[1].x, acc[1].y, acc[1].z, acc[1].w};
    float* dp = delta + (size_t)b * 65536 + l;
    for (int dd = 0; dd < 64; ++dd) {
        const float4* r = reinterpret_cast<const float4*>(&dw[dd * 8]);
        const float4 w0 = r[0], w1 = r[1];
        float s = dtb[dd];
        s = fmaf(dts[0], w0.x, s); s = fmaf(dts[1], w0.y, s);
        s = fmaf(dts[2], w0.z, s); s = fmaf(dts[3], w0.w, s);
        s = fmaf(dts[4], w1.x, s); s = fmaf(dts[5], w1.y, s);
        s = fmaf(dts[6], w1.z, s); s = fmaf(dts[7], w1.w, s);
        const float sp = fmaxf(s, 0.f) + log1pf(__expf(-fabsf(s)));
        dp[(size_t)dd * 1024] = sp;
    }
}

// ---------------- K4: chunked selective scan (one block per (b,d)) -----------
// thread t = (chunk c = t>>4, state n = t&15). Chunk = 64 timesteps.
// Pass 1: per-chunk affine reduction (P = prod dA, q = in-chunk response).
// LDS exchange -> each lane composes preceding chunks for its incoming h.
// Pass 2: re-run chunk with real h; y staged in LDS, ONE coalesced float4
// store of the whole (b,d) row at the end. y layout is now (b,d,l).
__global__ __launch_bounds__(256) void k4_scan(
    const float* __restrict__ delta, const float* __restrict__ u,
    const float* __restrict__ Bsp, const float* __restrict__ Csp,
    const float* __restrict__ A_logs, const float* __restrict__ Ds,
    float* __restrict__ y)
{
    __shared__ float Pb[16][17];
    __shared__ float qb[16][17];
    __shared__ float yl[1024];
    const int t = threadIdx.x;
    const int c = t >> 4;           // chunk index 0..15
    const int n = t & 15;           // state index 0..15
    const int pair = blockIdx.x;    // b*64 + d
    const int b = pair >> 6, d = pair & 63;

    const float Aval = -__expf(A_logs[d * 16 + n]);
    const float Dval = Ds[d];

    const float4* dp = reinterpret_cast<const float4*>(delta + ((size_t)b * 64 + d) * 1024 + c * 64);
    const float4* up = reinterpret_cast<const float4*>(u     + ((size_t)b * 64 + d) * 1024 + c * 64);
    const float4* Bp = reinterpret_cast<const float4*>(Bsp + ((size_t)b * 16 + n) * 1024 + c * 64);
    const float4* Cp = reinterpret_cast<const float4*>(Csp + ((size_t)b * 16 + n) * 1024 + c * 64);

    // ---- pass 1: chunk -> (P, q) ----
    float P = 1.f, q = 0.f;
#define P1_STEP(DJ, UJ, BJ)                          \
    {                                                \
        const float a = __expf((DJ) * Aval);         \
        P *= a;                                      \
        q = fmaf(a, q, (DJ) * (UJ) * (BJ));          \
    }
    for (int j4 = 0; j4 < 16; ++j4) {
        const float4 dv = dp[j4], uv = up[j4], bv = Bp[j4];
        P1_STEP(dv.x, uv.x, bv.x)
        P1_STEP(dv.y, uv.y, bv.y)
        P1_STEP(dv.z, uv.z, bv.z)
        P1_STEP(dv.w, uv.w, bv.w)
    }
#undef P1_STEP
    Pb[c][n] = P; qb[c][n] = q;
    __syncthreads();

    // incoming h for this chunk: compose chunks 0..c-1 applied to h=0
    float h = 0.f;
    for (int cc = 0; cc < c; ++cc)
        h = fmaf(Pb[cc][n], h, qb[cc][n]);

    // ---- pass 2: re-run chunk with real h ----
#define P2_STEP(DJ, UJ, BJ, CJ, YJ)                        \
    {                                                      \
        const float a = __expf((DJ) * Aval);               \
        h = fmaf(a, h, (DJ) * (UJ) * (BJ));                \
        float pz = h * (CJ);                               \
        pz += __shfl_xor(pz, 1); pz += __shfl_xor(pz, 2);  \
        pz += __shfl_xor(pz, 4); pz += __shfl_xor(pz, 8);  \
        YJ = fmaf(Dval, (UJ), pz);                         \
    }
    for (int j4 = 0; j4 < 16; ++j4) {
        const float4 dv = dp[j4], uv = up[j4], bv = Bp[j4], cv = Cp[j4];
        float y0, y1, y2, y3;
        P2_STEP(dv.x, uv.x, bv.x, cv.x, y0)
        P2_STEP(dv.y, uv.y, bv.y, cv.y, y1)
        P2_STEP(dv.z, uv.z, bv.z, cv.z, y2)
        P2_STEP(dv.w, uv.w, bv.w, cv.w, y3)
        // after full butterfly, y0..y3 are replicated in all 16 lanes of the
        // n-group; lanes n<4 deposit one timestep each (4-way bank alias).
        if (n < 4) {
            float yv = y0;
            if (n == 1) yv = y1;
            else if (n == 2) yv = y2;
            else if (n == 3) yv = y3;
            yl[c * 64 + j4 * 4 + n] = yv;
        }
    }
#undef P2_STEP
    __syncthreads();
    // one fully-coalesced row store: y(b,d,l)
    *reinterpret_cast<float4*>(&y[(size_t)pair * 1024 + t * 4]) =
        *reinterpret_cast<const float4*>(&yl[t * 4]);
}

// ---------------- K5: LayerNorm + silu(z) gate + out GEMM --------------------
// y is (b,d,l): transpose-load the 64x64 tile through LDS.
__global__ __launch_bounds__(256) void k5_out(
    const float* __restrict__ y, const float* __restrict__ z,
    const float* __restrict__ ln_g, const float* __restrict__ ln_b,
    const float* __restrict__ w_out, float* __restrict__ out)
{
    __shared__ float yn[64 * 68];   // [l_local][d] stride 68
    __shared__ float wo[64 * 132];  // [d][c] pad 132
    const int t  = threadIdx.x;
    const int p0 = blockIdx.x * 64;
    const int b  = p0 >> 10, l0 = p0 & 1023;

    for (int i = t; i < 8192; i += 256) {
        const int c = i >> 6, dd = i & 63;
        wo[dd * 132 + c] = w_out[i];
    }

    // transpose-load y tile: row d, cols l0..l0+63 (coalesced 64B per 4 lanes)
    {
        const int d = t >> 2;
        const float* yrow = y + ((size_t)b * 64 + d) * 1024 + l0;
#pragma unroll
        for (int k = 0; k < 4; ++k) {
            const int c4 = ((t & 3) + k * 4) * 4;
            const float4 v = *reinterpret_cast<const float4*>(&yrow[c4]);
            yn[(c4 + 0) * 68 + d] = v.x;
            yn[(c4 + 1) * 68 + d] = v.y;
            yn[(c4 + 2) * 68 + d] = v.z;
            yn[(c4 + 3) * 68 + d] = v.w;
        }
    }
    __syncthreads();

    const int lane = t & 63, wv = t >> 6;
    const float g = ln_g[lane], bbv = ln_b[lane];
#pragma unroll 1
    for (int i = 0; i < 16; ++i) {
        const int pl = wv * 16 + i;
        const size_t p = (size_t)p0 + pl;
        const float v  = yn[pl * 68 + lane];
        const float zv = z[p * 64 + lane];
        float s1 = v, s2 = v * v;
#pragma unroll
        for (int m = 1; m < 64; m <<= 1) {
            s1 += __shfl_xor(s1, m);
            s2 += __shfl_xor(s2, m);
        }
        const float mu   = s1 * (1.f / 64.f);
        const float var  = s2 * (1.f / 64.f) - mu * mu;
        const float rstd = rsqrtf(var + 1e-5f);
        const float sz   = zv / (1.f + __expf(-zv));
        yn[pl * 68 + lane] = ((v - mu) * rstd * g + bbv) * sz;
    }
    __syncthreads();

    const int tx = t & 31, ty = t >> 5;
    float acc[8][4];
#pragma unroll
    for (int i = 0; i < 8; ++i)
#pragma unroll
        for (int j = 0; j < 4; ++j) acc[i][j] = 0.f;

    for (int dd = 0; dd < 64; ++dd) {
        const float4 w4 = *reinterpret_cast<const float4*>(&wo[dd * 132 + (tx << 2)]);
#pragma unroll
        for (int i = 0; i < 8; ++i) {
            const float a = yn[(ty * 8 + i) * 68 + dd];
            acc[i][0] = fmaf(a, w4.x, acc[i][0]);
            acc[i][1] = fmaf(a, w4.y, acc[i][1]);
            acc[i][2] = fmaf(a, w4.z, acc[i][2]);
            acc[i][3] = fmaf(a, w4.w, acc[i][3]);
        }
    }
#pragma unroll
    for (int i = 0; i < 8; ++i) {
        const size_t p = (size_t)p0 + ty * 8 + i;
        *reinterpret_cast<float4*>(&out[p * 128 + (tx << 2)]) =
            make_float4(acc[i][0], acc[i][1], acc[i][2], acc[i][3]);
    }
}

extern "C" void kernel_launch(void* const* d_in, const int* in_sizes, int n_in,
                              void* d_out, int out_size, void* d_ws, size_t ws_size,
                              hipStream_t stream)
{
    const float* x        = (const float*)d_in[0];
    const float* w_in     = (const float*)d_in[1];
    const float* conv_w   = (const float*)d_in[2];
    const float* conv_b   = (const float*)d_in[3];
    const float* xproj_w  = (const float*)d_in[4];
    const float* dtproj_w = (const float*)d_in[5];
    const float* dtproj_b = (const float*)d_in[6];
    const float* A_logs   = (const float*)d_in[7];
    const float* Ds       = (const float*)d_in[8];
    const float* ln_g     = (const float*)d_in[9];
    const float* ln_b     = (const float*)d_in[10];
    const float* w_out    = (const float*)d_in[11];
    float* out = (float*)d_out;
    float* ws  = (float*)d_ws;

    const size_t M  = (size_t)2097152;  // 32*64*1024
    float* xc    = ws;                  // 8 MB
    float* z     = ws + M;              // 8 MB
    float* u     = ws + 2 * M;          // 8 MB
    float* delta = ws + 3 * M;          // 8 MB
    float* y     = ws + 4 * M;          // 8 MB  (b,d,l)
    float* Bsp   = ws + 5 * M;          // 2 MB
    float* Csp   = Bsp + 524288;        // 2 MB

    k1_gemm_in<<<512, 256, 0, stream>>>(x, w_in, xc, z);
    k2_conv<<<2048, 256, 0, stream>>>(xc, conv_w, conv_b, u);
    k3_xproj<<<128, 256, 0, stream>>>(u, xproj_w, dtproj_w, dtproj_b, delta, Bsp, Csp);
    k4_scan<<<2048, 256, 0, stream>>>(delta, u, Bsp, Csp, A_logs, Ds, y);
    k5_out<<<512, 256, 0, stream>>>(y, z, ln_g, ln_b, w_out, out);
}